// Round 1
// baseline (146.106 us; speedup 1.0000x reference)
//
#include <hip/hip_runtime.h>

#define SH_C0 0.28209479177387814f

// Compute viewmat = inv(ext) for ext = [[A, t],[0,0,0,1]] (true by construction),
// with the reference's translation scaling (sf = 1/near0 = 10) applied first.
__device__ __forceinline__ void view_from_ext(const float* e, float R[9], float t[3]) {
  const float sf = 10.0f;
  float a00=e[0],a01=e[1],a02=e[2], a10=e[4],a11=e[5],a12=e[6], a20=e[8],a21=e[9],a22=e[10];
  float tx=e[3]*sf, ty=e[7]*sf, tz=e[11]*sf;
  float c00 =  a11*a22 - a12*a21;
  float c01 = -(a10*a22 - a12*a20);
  float c02 =  a10*a21 - a11*a20;
  float det = a00*c00 + a01*c01 + a02*c02;
  float id = 1.0f/det;
  R[0]=c00*id;               R[1]=(a02*a21-a01*a22)*id; R[2]=(a01*a12-a02*a11)*id;
  R[3]=c01*id;               R[4]=(a00*a22-a02*a20)*id; R[5]=(a02*a10-a00*a12)*id;
  R[6]=c02*id;               R[7]=(a01*a20-a00*a21)*id; R[8]=(a00*a11-a01*a10)*id;
  t[0]=-(R[0]*tx+R[1]*ty+R[2]*tz);
  t[1]=-(R[3]*tx+R[4]*ty+R[5]*tz);
  t[2]=-(R[6]*tx+R[7]*ty+R[8]*tz);
}

// One block per view: compute camera-z keys, bitonic-argsort ascending (matches
// jnp.argsort; keys are distinct random floats so stability is moot).
__global__ __launch_bounds__(1024) void zsort_kernel(const float* __restrict__ means,
                                                     const float* __restrict__ ext,
                                                     int* __restrict__ order, int G) {
  __shared__ float key[2048];
  __shared__ int   val[2048];
  int v = blockIdx.x;
  int tid = threadIdx.x;
  float R[9], t[3];
  view_from_ext(ext + v*16, R, t);
  for (int i = tid; i < G; i += blockDim.x) {
    const float* m = means + (size_t)i*3;
    float z = R[6]*(m[0]*10.0f) + R[7]*(m[1]*10.0f) + R[8]*(m[2]*10.0f) + t[2];
    key[i] = z; val[i] = i;
  }
  for (int k = 2; k <= G; k <<= 1) {
    for (int j = k >> 1; j > 0; j >>= 1) {
      __syncthreads();
      for (int i = tid; i < G; i += blockDim.x) {
        int ixj = i ^ j;
        if (ixj > i) {
          float ki = key[i], kx = key[ixj];
          bool up = ((i & k) == 0);
          if (up ? (ki > kx) : (ki < kx)) {
            key[i] = kx; key[ixj] = ki;
            int tv = val[i]; val[i] = val[ixj]; val[ixj] = tv;
          }
        }
      }
    }
  }
  __syncthreads();
  for (int i = tid; i < G; i += blockDim.x) order[v*G + i] = val[i];
}

// Per (view, sorted-rank): full projection + conic. Writes 12-float packed record:
// [u, v, A', B', C', opac*valid, r, g, b, z, pad, pad] where
// power = A'*dx^2 + B'*dx*dy + C'*dy^2.
__global__ __launch_bounds__(256) void prep_kernel(
    const float* __restrict__ means, const float* __restrict__ covs,
    const float* __restrict__ sh, const float* __restrict__ opac,
    const float* __restrict__ ext, const float* __restrict__ intr,
    const int* __restrict__ order, float* __restrict__ sorted,
    int G, int V, float Wf, float Hf) {
  int i = blockIdx.x*256 + threadIdx.x;
  if (i >= V*G) return;
  int v = i / G;
  int g = order[i];
  float R[9], t[3];
  view_from_ext(ext + v*16, R, t);
  const float* Kv = intr + v*9;
  float fx = Kv[0]*Wf, cx = Kv[2]*Wf;
  float fy = Kv[4]*Hf, cy = Kv[5]*Hf;
  const float* m = means + (size_t)g*3;
  float mx = m[0]*10.0f, my = m[1]*10.0f, mz = m[2]*10.0f;
  float x = R[0]*mx + R[1]*my + R[2]*mz + t[0];
  float y = R[3]*mx + R[4]*my + R[5]*mz + t[1];
  float z = R[6]*mx + R[7]*my + R[8]*mz + t[2];
  float zc = fmaxf(z, 1e-6f);
  float u  = fx*x/zc + cx;
  float vv = fy*y/zc + cy;
  // covc = R * (cov*100) * R^T
  const float* C9 = covs + (size_t)g*9;
  float cs[9];
  #pragma unroll
  for (int q = 0; q < 9; ++q) cs[q] = C9[q]*100.0f;
  float tm[9], M[9];
  #pragma unroll
  for (int r2 = 0; r2 < 3; ++r2)
    #pragma unroll
    for (int c2 = 0; c2 < 3; ++c2)
      tm[r2*3+c2] = R[r2*3+0]*cs[c2] + R[r2*3+1]*cs[3+c2] + R[r2*3+2]*cs[6+c2];
  #pragma unroll
  for (int r2 = 0; r2 < 3; ++r2)
    #pragma unroll
    for (int c2 = 0; c2 < 3; ++c2)
      M[r2*3+c2] = tm[r2*3+0]*R[c2*3+0] + tm[r2*3+1]*R[c2*3+1] + tm[r2*3+2]*R[c2*3+2];
  // J = [[fx/zc, 0, -fx*x/zc^2], [0, fy/zc, -fy*y/zc^2]], cov2 = J M J^T
  float j0 = fx/zc, j2 = -fx*x/(zc*zc);
  float j1 = fy/zc, j3 = -fy*y/(zc*zc);
  float c00 = j0*(M[0]*j0 + M[2]*j2) + j2*(M[6]*j0 + M[8]*j2);
  float c01 = j0*(M[1]*j1 + M[2]*j3) + j2*(M[7]*j1 + M[8]*j3);
  float c11 = j1*(M[4]*j1 + M[5]*j3) + j3*(M[7]*j1 + M[8]*j3);
  float a = c00 + 0.3f, c = c11 + 0.3f, bq = c01;
  float det2 = a*c - bq*bq;
  float invd = 1.0f/fmaxf(det2, 1e-12f);
  bool valid = (z > 1.0f) && (z < 1000.0f) && (det2 > 0.0f);
  float op = valid ? opac[g] : 0.0f;
  float* o = sorted + (size_t)i*12;
  o[0] = u; o[1] = vv;
  o[2] = -0.5f*invd*c;   // A'
  o[3] =  invd*bq;       // B'
  o[4] = -0.5f*invd*a;   // C'
  o[5] = op;
  o[6] = SH_C0*sh[(size_t)g*3+0]+0.5f;
  o[7] = SH_C0*sh[(size_t)g*3+1]+0.5f;
  o[8] = SH_C0*sh[(size_t)g*3+2]+0.5f;
  o[9] = z; o[10] = 0.0f; o[11] = 0.0f;
}

// grid (P/1024, NCHUNK, V), 256 threads, 4 pixels/thread (keeps the per-CU LDS
// pipe under the VALU cost). Each block composites one gaussian chunk for 1024
// pixels, writing partial (T, Cr, Cg, Cb, D) for later z-ordered combining.
__global__ __launch_bounds__(256) void render_kernel(
    const float4* __restrict__ srt, float* __restrict__ partial,
    int G, int chunkSize, int P, int W) {
  __shared__ float4 sp[128*3];
  int tid = threadIdx.x;
  int view = blockIdx.z, chunk = blockIdx.y;
  int pixBase = blockIdx.x * 1024;
  float pxk[4], pyk[4];
  #pragma unroll
  for (int k = 0; k < 4; ++k) {
    int p = pixBase + tid + k*256;
    pxk[k] = (float)(p % W) + 0.5f;
    pyk[k] = (float)(p / W) + 0.5f;
  }
  float T[4]  = {1.0f,1.0f,1.0f,1.0f};
  float cr[4] = {0,0,0,0}, cg[4] = {0,0,0,0}, cb[4] = {0,0,0,0}, dp[4] = {0,0,0,0};
  int cstart = chunk * chunkSize, cend = cstart + chunkSize;
  for (int g0 = cstart; g0 < cend; g0 += 128) {
    int nt = min(128, cend - g0);
    __syncthreads();
    for (int q = tid; q < nt*3; q += 256)
      sp[q] = srt[((size_t)view*G + g0)*3 + q];
    __syncthreads();
    for (int i = 0; i < nt; ++i) {
      float4 q0 = sp[i*3+0], q1 = sp[i*3+1], q2 = sp[i*3+2];
      float u = q0.x, vv = q0.y, A = q0.z, B = q0.w;
      float Cc = q1.x, op = q1.y, r = q1.z, gcol = q1.w;
      float bcol = q2.x, z = q2.y;
      #pragma unroll
      for (int k = 0; k < 4; ++k) {
        float dx = pxk[k] - u, dy = pyk[k] - vv;
        float t1 = fmaf(B, dy, A*dx);
        float pw = fmaf(dx, t1, Cc*dy*dy);
        pw = fminf(pw, 0.0f);
        float al = fminf(op*__expf(pw), 0.999f);
        float w = T[k]*al;
        cr[k] = fmaf(w, r,    cr[k]);
        cg[k] = fmaf(w, gcol, cg[k]);
        cb[k] = fmaf(w, bcol, cb[k]);
        dp[k] = fmaf(w, z,    dp[k]);
        T[k] *= (1.0f - al);
      }
    }
  }
  size_t base = ((size_t)(view*gridDim.y + chunk))*5*(size_t)P;
  #pragma unroll
  for (int k = 0; k < 4; ++k) {
    int pix = pixBase + tid + k*256;
    partial[base + 0*(size_t)P + pix] = T[k];
    partial[base + 1*(size_t)P + pix] = cr[k];
    partial[base + 2*(size_t)P + pix] = cg[k];
    partial[base + 3*(size_t)P + pix] = cb[k];
    partial[base + 4*(size_t)P + pix] = dp[k];
  }
}

// Fold chunk partials in z order: C = C1 + T1*(C2 + T2*(...)), T = prod(Ti).
__global__ __launch_bounds__(256) void combine_kernel(
    const float* __restrict__ partial, float* __restrict__ out,
    int NC, int P, int V) {
  int id = blockIdx.x*256 + threadIdx.x;
  if (id >= V*P) return;
  int view = id / P, pix = id - view*P;
  float T = 1.0f, cr = 0, cg = 0, cb = 0, dp = 0;
  for (int c2 = 0; c2 < NC; ++c2) {
    const float* b = partial + ((size_t)(view*NC + c2))*5*(size_t)P + pix;
    float t  = b[0];
    cr = fmaf(T, b[1*(size_t)P], cr);
    cg = fmaf(T, b[2*(size_t)P], cg);
    cb = fmaf(T, b[3*(size_t)P], cb);
    dp = fmaf(T, b[4*(size_t)P], dp);
    T *= t;
  }
  out[(size_t)(view*3+0)*P + pix] = fminf(fmaxf(cr, 0.0f), 1.0f);
  out[(size_t)(view*3+1)*P + pix] = fminf(fmaxf(cg, 0.0f), 1.0f);
  out[(size_t)(view*3+2)*P + pix] = fminf(fmaxf(cb, 0.0f), 1.0f);
  out[(size_t)V*3*P + (size_t)view*P + pix] = dp;
}

extern "C" void kernel_launch(void* const* d_in, const int* in_sizes, int n_in,
                              void* d_out, int out_size, void* d_ws, size_t ws_size,
                              hipStream_t stream) {
  const float* means = (const float*)d_in[0];
  const float* covs  = (const float*)d_in[1];
  const float* sh    = (const float*)d_in[2];
  const float* opac  = (const float*)d_in[3];
  const float* ext   = (const float*)d_in[4];
  const float* intr  = (const float*)d_in[5];
  const int G = in_sizes[0] / 3;   // 2048 (b=1)
  const int V = in_sizes[4] / 16;  // 2
  const int H = 96, W = 96, P = H*W;  // fixed by setup_inputs

  char* ws = (char*)d_ws;
  int* order = (int*)ws;  // V*G ints
  size_t off  = (((size_t)V*G*sizeof(int)) + 255) & ~(size_t)255;
  float* sorted = (float*)(ws + off);  // V*G*12 floats, 16B-aligned records
  size_t off2 = (off + (size_t)V*G*12*sizeof(float) + 255) & ~(size_t)255;
  float* partial = (float*)(ws + off2);
  size_t avail = ws_size > off2 ? ws_size - off2 : 0;
  int NC = 32;
  while (NC > 1 && (size_t)V*NC*5*(size_t)P*sizeof(float) > avail) NC >>= 1;
  int chunkSize = G / NC;

  zsort_kernel<<<V, 1024, 0, stream>>>(means, ext, order, G);
  prep_kernel<<<(V*G + 255)/256, 256, 0, stream>>>(means, covs, sh, opac, ext, intr,
                                                   order, sorted, G, V, (float)W, (float)H);
  dim3 gc(P/1024, NC, V);
  render_kernel<<<gc, 256, 0, stream>>>((const float4*)sorted, partial, G, chunkSize, P, W);
  combine_kernel<<<(V*P + 255)/256, 256, 0, stream>>>(partial, (float*)d_out, NC, P, V);
}